// Round 12
// baseline (359.621 us; speedup 1.0000x reference)
//
#include <hip/hip_runtime.h>
#include <cstddef>

#define N_     2048
#define H_     32
#define NEGF   (-1.0e30f)
#define LOG2E  1.4426950408889634f
#define C1F    (0.17677669529663687f * 1.4426950408889634f)   // (1/sqrt(32))*log2e
#define DEFER  16.0f
#define NCHUNK 32
#define CLEN   64             // N_/NCHUNK
#define NRTOT  8192           // B*N

#define AS1 __attribute__((address_space(1)))
#define AS3 __attribute__((address_space(3)))

__device__ __forceinline__ float exp2_fast(float x) {
    float r;
    asm("v_exp_f32 %0, %1" : "=v"(r) : "v"(x));
    return r;
}

// ---------------------------------------------------------------- adj -> bitmask
__global__ __launch_bounds__(256) void k_adjmask(const int* __restrict__ adj,
                                                 unsigned long long* __restrict__ mask) {
    size_t idx = (size_t)blockIdx.x * 256 + threadIdx.x;     // over B*N*N
    unsigned long long m = __ballot(adj[idx] != 0);
    if ((threadIdx.x & 63) == 0) mask[idx >> 6] = m;
}

// ---------------------------------------------------------------- init h
__global__ __launch_bounds__(256) void k_init_h(const float* __restrict__ feats,
                                                const float* __restrict__ W_in,
                                                float* __restrict__ h) {
    int idx = blockIdx.x * 256 + threadIdx.x;       // B*N*32 total
    int bn  = idx >> 5, c = idx & 31;
    float f0 = feats[bn * 3 + 0], f1 = feats[bn * 3 + 1], f2 = feats[bn * 3 + 2];
    h[idx] = f0 * W_in[c] + f1 * W_in[32 + c] + f2 * W_in[64 + c];
}

// ---------------------------------------------------------------- q,k,v
__global__ __launch_bounds__(256) void k_qkv(const float* __restrict__ h,
                                             const float* __restrict__ Wq,
                                             const float* __restrict__ Wk,
                                             const float* __restrict__ Wv,
                                             float* __restrict__ q,
                                             float* __restrict__ k,
                                             float* __restrict__ v) {
    __shared__ float hs[8][33];
    int t = threadIdx.x;
    int rl = t >> 5, c = t & 31;
    int row = blockIdx.x * 8 + rl;
    hs[rl][c] = h[(row << 5) + c];
    __syncthreads();
    float aq = 0.f, ak = 0.f, av = 0.f;
#pragma unroll
    for (int d = 0; d < 32; ++d) {
        float hd = hs[rl][d];
        aq += hd * Wq[(d << 5) + c];
        ak += hd * Wk[(d << 5) + c];
        av += hd * Wv[(d << 5) + c];
    }
    q[(row << 5) + c] = aq;
    k[(row << 5) + c] = ak;
    v[(row << 5) + c] = av;
}

// ---------------------------------------------------------------- attention core (d-split lane pairs)
// Lane pair (2l,2l+1) jointly owns 4 rows; even lane = d[0,16), odd = d[16,32).
// Each lane: 4 half K reads + 4 half V reads + 1 x read per jj -> 9 b128,
// serving 256 (row,j) pairs/wave/jj (72B LDS per pair vs 136B for full-d).
// Partial dots completed by __shfl_xor(.,1) (bit-identical both lanes).
// __launch_bounds__(256,1): this toolchain caps arch-VGPR at 256/W for arg W
// (empirical: R2 arg4->64, R11 arg2->128) -- arg 1 gives the ~220-reg live
// set real registers, no spill.
__global__ __launch_bounds__(256, 1) void k_attn(const float* __restrict__ qg,
                                                 const float* __restrict__ kg,
                                                 const float* __restrict__ vg,
                                                 const float* __restrict__ xin,
                                                 const unsigned long long* __restrict__ maskg,
                                                 float* __restrict__ pm,
                                                 float* __restrict__ ps,
                                                 float* __restrict__ pacc) {
    __shared__ __attribute__((aligned(16))) float k_lds[CLEN * 32];
    __shared__ __attribute__((aligned(16))) float v_lds[CLEN * 32];
    __shared__ __attribute__((aligned(16))) float x_lds[CLEN * 4];

    const int t    = threadIdx.x;
    const int w    = t >> 6, lane = t & 63;
    const int pairId = lane >> 1, half = lane & 1;
    const int hoff = half << 4;              // float offset of this lane's d-half
    const int rg   = blockIdx.x >> 5;        // 16 row-groups of 512 rows
    const int cid  = blockIdx.x & 31;        // 32 chunks
    const int bN   = (rg >> 2) << 11;
    const int j0   = cid << 6;
    const int rbase = (rg << 9) + (w << 7) + pairId;   // rows rbase + 32*i, i=0..3

    // ---- stage K/V chunk (linear global_load_lds) + x chunk
    const float* kbase = kg + (((size_t)(bN + j0)) << 5);
    const float* vbase = vg + (((size_t)(bN + j0)) << 5);
#pragma unroll
    for (int i = 0; i < 2; ++i) {
        int f = t + (i << 8);            // float4 index 0..511
        __builtin_amdgcn_global_load_lds((const AS1 void*)(kbase + (f << 2)),
            (AS3 void*)((char*)k_lds + (f << 4)), 16, 0, 0);
        __builtin_amdgcn_global_load_lds((const AS1 void*)(vbase + (f << 2)),
            (AS3 void*)((char*)v_lds + (f << 4)), 16, 0, 0);
    }
    if (t < CLEN) {
        const float* xp = xin + ((size_t)(bN + j0 + t)) * 3;
        float4 xv; xv.x = xp[0]; xv.y = xp[1]; xv.z = xp[2]; xv.w = 0.f;
        *(float4*)(x_lds + (t << 2)) = xv;
    }

    // ---- per-lane state: 4 rows, half-d each
    float qr[4][16];
    float xi[4][3];
    unsigned long long mw[4];
#pragma unroll
    for (int i = 0; i < 4; ++i) {
        const int r = rbase + (i << 5);
        const float4* qp = (const float4*)(qg + (((size_t)r) << 5) + hoff);
#pragma unroll
        for (int c = 0; c < 4; ++c) {
            float4 qv = qp[c];
            qr[i][4*c]   = qv.x * C1F; qr[i][4*c+1] = qv.y * C1F;
            qr[i][4*c+2] = qv.z * C1F; qr[i][4*c+3] = qv.w * C1F;
        }
        xi[i][0] = xin[r*3+0]; xi[i][1] = xin[r*3+1]; xi[i][2] = xin[r*3+2];
        mw[i] = maskg[(((size_t)r) << 5) + cid];
    }

    float acc[4][16];
    float xacc[4][3];
    float m[4], sum[4];
#pragma unroll
    for (int i = 0; i < 4; ++i) {
#pragma unroll
        for (int c = 0; c < 16; ++c) acc[i][c] = 0.f;
        xacc[i][0] = 0.f; xacc[i][1] = 0.f; xacc[i][2] = 0.f;
        m[i] = NEGF; sum[i] = 0.f;
    }

    __syncthreads();     // staging complete

#pragma unroll 2
    for (int jj = 0; jj < CLEN; ++jj) {
        const float4* kp = (const float4*)(k_lds + (jj << 5) + hoff);
        float4 k0 = kp[0], k1 = kp[1], k2 = kp[2], k3 = kp[3];
        float dot[4];
#pragma unroll
        for (int i = 0; i < 4; ++i) {
            float pA = fmaf(qr[i][0], k0.x, fmaf(qr[i][1], k0.y,
                       fmaf(qr[i][2], k0.z, qr[i][3] * k0.w)));
            float pB = fmaf(qr[i][4], k1.x, fmaf(qr[i][5], k1.y,
                       fmaf(qr[i][6], k1.z, qr[i][7] * k1.w)));
            float pC = fmaf(qr[i][8], k2.x, fmaf(qr[i][9], k2.y,
                       fmaf(qr[i][10], k2.z, qr[i][11] * k2.w)));
            float pD = fmaf(qr[i][12], k3.x, fmaf(qr[i][13], k3.y,
                       fmaf(qr[i][14], k3.z, qr[i][15] * k3.w)));
            dot[i] = (pA + pB) + (pC + pD);
        }
#pragma unroll
        for (int i = 0; i < 4; ++i) dot[i] += __shfl_xor(dot[i], 1);

        float4 xj = *(const float4*)(x_lds + (jj << 2));
        float se[4];
#pragma unroll
        for (int i = 0; i < 4; ++i) {
            float d0 = xi[i][0] - xj.x, d1 = xi[i][1] - xj.y, d2 = xi[i][2] - xj.z;
            float dist = fmaf(d2, d2, fmaf(d1, d1, d0 * d0));
            se[i] = (mw[i] & 1ULL) ? fmaf(dist, -LOG2E, dot[i]) : NEGF;
            mw[i] >>= 1;
        }

        if (__any(int(se[0] - m[0] > DEFER) | int(se[1] - m[1] > DEFER) |
                  int(se[2] - m[2] > DEFER) | int(se[3] - m[3] > DEFER))) {
#pragma unroll
            for (int i = 0; i < 4; ++i) {
                float nm = fmaxf(m[i], se[i]);
                float al = exp2_fast(m[i] - nm);
                m[i] = nm; sum[i] *= al;
#pragma unroll
                for (int c = 0; c < 16; ++c) acc[i][c] *= al;
                xacc[i][0] *= al; xacc[i][1] *= al; xacc[i][2] *= al;
            }
        }

        const float4* vp = (const float4*)(v_lds + (jj << 5) + hoff);
        float4 v0 = vp[0], v1 = vp[1], v2 = vp[2], v3 = vp[3];
#pragma unroll
        for (int i = 0; i < 4; ++i) {
            float p = exp2_fast(se[i] - m[i]);
            sum[i] += p;
            acc[i][0]  = fmaf(p, v0.x, acc[i][0]);
            acc[i][1]  = fmaf(p, v0.y, acc[i][1]);
            acc[i][2]  = fmaf(p, v0.z, acc[i][2]);
            acc[i][3]  = fmaf(p, v0.w, acc[i][3]);
            acc[i][4]  = fmaf(p, v1.x, acc[i][4]);
            acc[i][5]  = fmaf(p, v1.y, acc[i][5]);
            acc[i][6]  = fmaf(p, v1.z, acc[i][6]);
            acc[i][7]  = fmaf(p, v1.w, acc[i][7]);
            acc[i][8]  = fmaf(p, v2.x, acc[i][8]);
            acc[i][9]  = fmaf(p, v2.y, acc[i][9]);
            acc[i][10] = fmaf(p, v2.z, acc[i][10]);
            acc[i][11] = fmaf(p, v2.w, acc[i][11]);
            acc[i][12] = fmaf(p, v3.x, acc[i][12]);
            acc[i][13] = fmaf(p, v3.y, acc[i][13]);
            acc[i][14] = fmaf(p, v3.z, acc[i][14]);
            acc[i][15] = fmaf(p, v3.w, acc[i][15]);
            xacc[i][0] = fmaf(p, xj.x, xacc[i][0]);
            xacc[i][1] = fmaf(p, xj.y, xacc[i][1]);
            xacc[i][2] = fmaf(p, xj.z, xacc[i][2]);
        }
    }

    // ---- write partials: stats [r][32] (even lane), acc [c][r][36] half per lane
#pragma unroll
    for (int i = 0; i < 4; ++i) {
        const int r = rbase + (i << 5);
        float* pbase = pacc + ((size_t)cid * NRTOT + r) * 36;
#pragma unroll
        for (int c = 0; c < 4; ++c) {
            float4 st; st.x = acc[i][4*c]; st.y = acc[i][4*c+1];
            st.z = acc[i][4*c+2]; st.w = acc[i][4*c+3];
            *(float4*)(pbase + hoff + (c << 2)) = st;
        }
        if (half == 0) {
            float4 st; st.x = xacc[i][0]; st.y = xacc[i][1]; st.z = xacc[i][2]; st.w = 0.f;
            *(float4*)(pbase + 32) = st;
            pm[(((size_t)r) << 5) + cid] = m[i];
            ps[(((size_t)r) << 5) + cid] = sum[i];
        }
    }
}

// ---------------------------------------------------------------- merge + epilogue, wave-per-row
__global__ __launch_bounds__(256) void k_mergefin(const float* __restrict__ pm,
                                                  const float* __restrict__ ps,
                                                  const float* __restrict__ pacc,
                                                  float* __restrict__ hg,
                                                  const float* __restrict__ xin,
                                                  float* __restrict__ xout,
                                                  const float* __restrict__ Wo,
                                                  const float* __restrict__ W1,
                                                  const float* __restrict__ W2,
                                                  const float* __restrict__ csp) {
    __shared__ float wo_s[1024];
    __shared__ float w1_s[2048];
    __shared__ float w2_s[2048];
    __shared__ float ad_s[4][40];
    __shared__ float h1_s[4][36];
    __shared__ float f_s[4][64];

    const int t = threadIdx.x, w = t >> 6, lane = t & 63;
    for (int i = t; i < 1024; i += 256) wo_s[i] = Wo[i];
    for (int i = t; i < 2048; i += 256) { w1_s[i] = W1[i]; w2_s[i] = W2[i]; }
    __syncthreads();

    const int r = (blockIdx.x << 2) + w;

    // merge stats across 32 chunks ([r][32] layout -> coalesced per wave)
    float pmv = NEGF, psv = 0.f;
    if (lane < NCHUNK) { pmv = pm[((size_t)r << 5) + lane]; psv = ps[((size_t)r << 5) + lane]; }
    float m_g = pmv;
#pragma unroll
    for (int off = 1; off < 64; off <<= 1) m_g = fmaxf(m_g, __shfl_xor(m_g, off));
    float scv = (lane < NCHUNK) ? exp2_fast(pmv - m_g) : 0.f;
    float sg = scv * psv;
#pragma unroll
    for (int off = 1; off < 64; off <<= 1) sg += __shfl_xor(sg, off);
    const float rinv = 1.0f / sg;

    // merged accumulator, lane = d (pacc [c][r][36], lane-contiguous reads)
    const int dl = (lane < 36) ? lane : 0;
    float ad = 0.f;
#pragma unroll
    for (int c = 0; c < NCHUNK; ++c) {
        float scc = __shfl(scv, c);
        float pv = pacc[((size_t)c * NRTOT + r) * 36 + dl];
        ad = fmaf(scc, pv, ad);
    }
    if (lane < 35) ad_s[w][lane] = ad;

    // Wo matmul: lane&31 = col (both halves compute redundantly)
    const int col = lane & 31;
    float hv = 0.f;
#pragma unroll
    for (int d = 0; d < 32; ++d) hv = fmaf(ad_s[w][d], wo_s[(d << 5) + col], hv);
    float h1 = 0.f;
    if (lane < 32) { h1 = hg[(((size_t)r) << 5) + lane] + hv * rinv; h1_s[w][lane] = h1; }

    // FF up: lane = u (64)
    float f = 0.f;
#pragma unroll
    for (int d = 0; d < 32; ++d) f = fmaf(h1_s[w][d], w1_s[(d << 6) + lane], f);
    f = fmaxf(f, 0.f);
    f_s[w][lane] = f;

    // FF down + residual: lane<32 = col
    if (lane < 32) {
        float v2a = 0.f;
#pragma unroll
        for (int u = 0; u < 64; ++u) v2a = fmaf(f_s[w][u], w2_s[(u << 5) + lane], v2a);
        hg[(((size_t)r) << 5) + lane] = h1 + v2a;
    }

    // equivariant x update
    if (lane < 3) {
        float o  = ad_s[w][32 + lane] * rinv;
        float xi = xin[r * 3 + lane];
        xout[r * 3 + lane] = xi + csp[0] * (xi - o);
    }
}

// ---------------------------------------------------------------- pooling stage 1 (parallel)
__global__ __launch_bounds__(256) void k_pool(const float* __restrict__ h,
                                              float* __restrict__ pool_ws) {
    const int b = blockIdx.x >> 5, sub = blockIdx.x & 31;
    const int t = threadIdx.x, c = t & 31, g = t >> 5;
    float s = 0.f;
#pragma unroll
    for (int i = 0; i < 8; ++i) {
        int row = (sub << 6) + (g << 3) + i;
        s += h[(((size_t)((b << 11) + row)) << 5) + c];
    }
    __shared__ float pool[8][32];
    pool[g][c] = s;
    __syncthreads();
    if (t < 32) {
        float ss = 0.f;
#pragma unroll
        for (int gg = 0; gg < 8; ++gg) ss += pool[gg][t];
        pool_ws[((b << 5) + sub) * 32 + t] = ss;
    }
}

// ---------------------------------------------------------------- head (tiny)
__global__ __launch_bounds__(256) void k_head(const float* __restrict__ pool_ws,
                                              const float* __restrict__ Wf1,
                                              const float* __restrict__ bf1,
                                              const float* __restrict__ Wf2,
                                              const float* __restrict__ bf2,
                                              float* __restrict__ out) {
    __shared__ float pooled[4][32];
    __shared__ float a1[4][16];
    const int t = threadIdx.x;
    if (t < 128) {
        int b = t >> 5, c = t & 31;
        float ss = 0.f;
#pragma unroll
        for (int sub = 0; sub < 32; ++sub) ss += pool_ws[((b << 5) + sub) * 32 + c];
        pooled[b][c] = ss * (1.0f / N_);
    }
    __syncthreads();
    if (t < 64) {
        int b = t >> 4, u = t & 15;
        float a = bf1[u];
#pragma unroll
        for (int d = 0; d < 32; ++d) a += pooled[b][d] * Wf1[(d << 4) + u];
        a1[b][u] = fmaxf(a, 0.f);
    }
    __syncthreads();
    if (t < 12) {
        int b = t / 3, o = t - b * 3;
        float v = bf2[o];
#pragma unroll
        for (int e = 0; e < 16; ++e) v += a1[b][e] * Wf2[e * 3 + o];
        out[b * 3 + o] = v;
    }
}

// ---------------------------------------------------------------- launch
extern "C" void kernel_launch(void* const* d_in, const int* in_sizes, int n_in,
                              void* d_out, int out_size, void* d_ws, size_t ws_size,
                              hipStream_t stream) {
    const float* feats = (const float*)d_in[0];
    const float* coors = (const float*)d_in[1];
    const int*   adj   = (const int*)d_in[2];
    const float* W_in  = (const float*)d_in[3];
    const float* Wq    = (const float*)d_in[4];
    const float* Wk    = (const float*)d_in[5];
    const float* Wv    = (const float*)d_in[6];
    const float* Wo    = (const float*)d_in[7];
    const float* W1    = (const float*)d_in[8];
    const float* W2    = (const float*)d_in[9];
    const float* csc   = (const float*)d_in[10];
    const float* Wf1   = (const float*)d_in[11];
    const float* bf1   = (const float*)d_in[12];
    const float* Wf2   = (const float*)d_in[13];
    const float* bf2   = (const float*)d_in[14];

    const size_t BNH = (size_t)4 * N_ * H_;   // 262144
    float* ws = (float*)d_ws;
    float* h  = ws;
    float* q  = ws + BNH;
    float* k  = ws + 2 * BNH;
    float* v  = ws + 3 * BNH;
    float* x0 = ws + 4 * BNH;                          // 24576 floats
    float* x1 = x0 + (size_t)4 * N_ * 3;
    unsigned long long* mask = (unsigned long long*)(x1 + (size_t)4 * N_ * 3);  // 262144 u64
    float* pm   = (float*)(mask + 262144);             // 262144
    float* ps   = pm + (size_t)NCHUNK * NRTOT;         // 262144
    float* pacc = ps + (size_t)NCHUNK * NRTOT;         // 32*8192*36 floats (37.7MB)
    float* pool_ws = pacc + (size_t)NCHUNK * NRTOT * 36;  // 4096 floats

    k_adjmask<<<65536, 256, 0, stream>>>(adj, mask);
    k_init_h<<<1024, 256, 0, stream>>>(feats, W_in, h);

    const float* xin[3]  = {coors, x0, x1};
    float*       xout[3] = {x0, x1, x0};
    for (int l = 0; l < 3; ++l) {
        k_qkv<<<1024, 256, 0, stream>>>(h, Wq + l * 1024, Wk + l * 1024, Wv + l * 1024, q, k, v);
        k_attn<<<512, 256, 0, stream>>>(q, k, v, xin[l], mask, pm, ps, pacc);
        k_mergefin<<<2048, 256, 0, stream>>>(pm, ps, pacc, h, xin[l], xout[l],
                                             Wo + l * 1024, W1 + l * 2048, W2 + l * 2048,
                                             csc + l);
    }
    k_pool<<<128, 256, 0, stream>>>(h, pool_ws);
    k_head<<<1, 256, 0, stream>>>(pool_ws, Wf1, bf1, Wf2, bf2, (float*)d_out);
}

// Round 13
// 259.901 us; speedup vs baseline: 1.3837x; 1.3837x over previous
//
#include <hip/hip_runtime.h>
#include <cstddef>

#define N_     2048
#define H_     32
#define NEGF   (-1.0e30f)
#define LOG2E  1.4426950408889634f
#define C1F    (0.17677669529663687f * 1.4426950408889634f)   // (1/sqrt(32))*log2e
#define DEFER  16.0f
#define NCHUNK 32
#define CLEN   64             // N_/NCHUNK
#define NRTOT  8192           // B*N

#define AS1 __attribute__((address_space(1)))
#define AS3 __attribute__((address_space(3)))

typedef float v2f __attribute__((ext_vector_type(2)));

__device__ __forceinline__ float exp2_fast(float x) {
    float r;
    asm("v_exp_f32 %0, %1" : "=v"(r) : "v"(x));
    return r;
}

// ---------------------------------------------------------------- adj -> bitmask
__global__ __launch_bounds__(256) void k_adjmask(const int* __restrict__ adj,
                                                 unsigned long long* __restrict__ mask) {
    size_t idx = (size_t)blockIdx.x * 256 + threadIdx.x;     // over B*N*N
    unsigned long long m = __ballot(adj[idx] != 0);
    if ((threadIdx.x & 63) == 0) mask[idx >> 6] = m;
}

// ---------------------------------------------------------------- fused h-init + layer-0 qkv
__global__ __launch_bounds__(256) void k_init_qkv(const float* __restrict__ feats,
                                                  const float* __restrict__ W_in,
                                                  const float* __restrict__ Wq,
                                                  const float* __restrict__ Wk,
                                                  const float* __restrict__ Wv,
                                                  float* __restrict__ h,
                                                  float* __restrict__ q,
                                                  float* __restrict__ k,
                                                  float* __restrict__ v) {
    __shared__ float hs[8][33];
    int t = threadIdx.x;
    int rl = t >> 5, c = t & 31;
    int row = blockIdx.x * 8 + rl;
    float f0 = feats[row * 3 + 0], f1 = feats[row * 3 + 1], f2 = feats[row * 3 + 2];
    float hv = f0 * W_in[c] + f1 * W_in[32 + c] + f2 * W_in[64 + c];
    hs[rl][c] = hv;
    h[(row << 5) + c] = hv;
    __syncthreads();
    float aq = 0.f, ak = 0.f, av = 0.f;
#pragma unroll
    for (int d = 0; d < 32; ++d) {
        float hd = hs[rl][d];
        aq += hd * Wq[(d << 5) + c];
        ak += hd * Wk[(d << 5) + c];
        av += hd * Wv[(d << 5) + c];
    }
    q[(row << 5) + c] = aq;
    k[(row << 5) + c] = ak;
    v[(row << 5) + c] = av;
}

// ---------------------------------------------------------------- attention core (round-10 proven version)
// 2 rows/lane, 512 rows/block, CLEN=64 j-chunk in LDS (wave-uniform broadcast
// reads). Partials: pm/ps [r][32], pacc [c][r][36] (contiguous per (c,r)).
__global__ __launch_bounds__(256, 2) void k_attn(const float* __restrict__ qg,
                                                 const float* __restrict__ kg,
                                                 const float* __restrict__ vg,
                                                 const float* __restrict__ xin,
                                                 const unsigned long long* __restrict__ maskg,
                                                 float* __restrict__ pm,
                                                 float* __restrict__ ps,
                                                 float* __restrict__ pacc) {
    __shared__ __attribute__((aligned(16))) float k_lds[CLEN * 32];
    __shared__ __attribute__((aligned(16))) float v_lds[CLEN * 32];
    __shared__ __attribute__((aligned(16))) float x_lds[CLEN * 4];

    const int t    = threadIdx.x;
    const int w    = t >> 6, lane = t & 63;
    const int rg   = blockIdx.x >> 5;        // 16 row-groups of 512 rows
    const int cid  = blockIdx.x & 31;        // 32 chunks
    const int b    = rg >> 2;
    const int bN   = b << 11;
    const int j0   = cid << 6;
    const int r0   = (rg << 9) + (w << 6) + lane;
    const int r1   = r0 + 256;

    // ---- stage K/V chunk (linear global_load_lds) + x chunk
    const float* kbase = kg + (((size_t)(bN + j0)) << 5);
    const float* vbase = vg + (((size_t)(bN + j0)) << 5);
#pragma unroll
    for (int i = 0; i < 2; ++i) {
        int f = t + (i << 8);            // float4 index 0..511
        __builtin_amdgcn_global_load_lds((const AS1 void*)(kbase + (f << 2)),
            (AS3 void*)((char*)k_lds + (f << 4)), 16, 0, 0);
        __builtin_amdgcn_global_load_lds((const AS1 void*)(vbase + (f << 2)),
            (AS3 void*)((char*)v_lds + (f << 4)), 16, 0, 0);
    }
    if (t < CLEN) {
        const float* xp = xin + ((size_t)(bN + j0 + t)) * 3;
        float4 xv; xv.x = xp[0]; xv.y = xp[1]; xv.z = xp[2]; xv.w = 0.f;
        *(float4*)(x_lds + (t << 2)) = xv;
    }

    // ---- per-lane 2-row state (packed pairs)
    v2f q2a[16], q2b[16];
#pragma unroll
    for (int d = 0; d < 32; d += 4) {
        float4 a = *(const float4*)(qg + (((size_t)r0) << 5) + d);
        v2f lo; lo.x = a.x * C1F; lo.y = a.y * C1F;
        v2f hi; hi.x = a.z * C1F; hi.y = a.w * C1F;
        q2a[d >> 1] = lo; q2a[(d >> 1) + 1] = hi;
        float4 bb = *(const float4*)(qg + (((size_t)r1) << 5) + d);
        v2f lo2; lo2.x = bb.x * C1F; lo2.y = bb.y * C1F;
        v2f hi2; hi2.x = bb.z * C1F; hi2.y = bb.w * C1F;
        q2b[d >> 1] = lo2; q2b[(d >> 1) + 1] = hi2;
    }
    const float xa0 = xin[r0 * 3 + 0], xa1 = xin[r0 * 3 + 1], xa2 = xin[r0 * 3 + 2];
    const float xb0 = xin[r1 * 3 + 0], xb1 = xin[r1 * 3 + 1], xb2 = xin[r1 * 3 + 2];
    unsigned long long mwa = maskg[((size_t)r0 << 5) + cid];
    unsigned long long mwb = maskg[((size_t)r1 << 5) + cid];

    v2f acc2a[16], acc2b[16];
#pragma unroll
    for (int c2 = 0; c2 < 16; ++c2) {
        acc2a[c2].x = 0.f; acc2a[c2].y = 0.f;
        acc2b[c2].x = 0.f; acc2b[c2].y = 0.f;
    }
    float aa0 = 0.f, aa1 = 0.f, aa2 = 0.f;   // x-accumulator row0
    float ab0 = 0.f, ab1 = 0.f, ab2 = 0.f;   // x-accumulator row1
    float m0 = NEGF, m1 = NEGF, sum0 = 0.f, sum1 = 0.f;

    __syncthreads();     // staging complete

#pragma unroll 4
    for (int jj = 0; jj < CLEN; ++jj) {
        const int bit0 = (int)(mwa & 1ULL); mwa >>= 1;
        const int bit1 = (int)(mwb & 1ULL); mwb >>= 1;
        const float4* kr = (const float4*)(k_lds + (jj << 5));
        v2f Pa0 = {0.f,0.f}, Pa1 = {0.f,0.f}, Pb0 = {0.f,0.f}, Pb1 = {0.f,0.f};
#pragma unroll
        for (int c = 0; c < 8; ++c) {
            float4 k4 = kr[c];
            v2f kl; kl.x = k4.x; kl.y = k4.y;
            v2f kh; kh.x = k4.z; kh.y = k4.w;
            Pa0 = __builtin_elementwise_fma(q2a[2 * c],     kl, Pa0);
            Pa1 = __builtin_elementwise_fma(q2a[2 * c + 1], kh, Pa1);
            Pb0 = __builtin_elementwise_fma(q2b[2 * c],     kl, Pb0);
            Pb1 = __builtin_elementwise_fma(q2b[2 * c + 1], kh, Pb1);
        }
        v2f Sa = Pa0 + Pa1, Sb = Pb0 + Pb1;
        float dot0 = Sa.x + Sa.y, dot1 = Sb.x + Sb.y;

        float4 xj = *(const float4*)(x_lds + (jj << 2));
        float da0 = xa0 - xj.x, da1 = xa1 - xj.y, da2 = xa2 - xj.z;
        float db0 = xb0 - xj.x, db1 = xb1 - xj.y, db2 = xb2 - xj.z;
        float dista = fmaf(da2, da2, fmaf(da1, da1, da0 * da0));
        float distb = fmaf(db2, db2, fmaf(db1, db1, db0 * db0));
        float se0 = bit0 ? fmaf(dista, -LOG2E, dot0) : NEGF;
        float se1 = bit1 ? fmaf(distb, -LOG2E, dot1) : NEGF;

        if (__any(int(se0 - m0 > DEFER) | int(se1 - m1 > DEFER))) {
            float n0 = fmaxf(m0, se0), n1 = fmaxf(m1, se1);
            float al0 = exp2_fast(m0 - n0), al1 = exp2_fast(m1 - n1);
            m0 = n0; m1 = n1;
            sum0 *= al0; sum1 *= al1;
            v2f av0; av0.x = al0; av0.y = al0;
            v2f av1; av1.x = al1; av1.y = al1;
#pragma unroll
            for (int c2 = 0; c2 < 16; ++c2) { acc2a[c2] *= av0; acc2b[c2] *= av1; }
            aa0 *= al0; aa1 *= al0; aa2 *= al0;
            ab0 *= al1; ab1 *= al1; ab2 *= al1;
        }
        float p0 = exp2_fast(se0 - m0);
        float p1 = exp2_fast(se1 - m1);
        sum0 += p0; sum1 += p1;
        v2f pv0; pv0.x = p0; pv0.y = p0;
        v2f pv1; pv1.x = p1; pv1.y = p1;
        const float4* vr = (const float4*)(v_lds + (jj << 5));
#pragma unroll
        for (int c = 0; c < 8; ++c) {
            float4 v4 = vr[c];
            v2f vl; vl.x = v4.x; vl.y = v4.y;
            v2f vh; vh.x = v4.z; vh.y = v4.w;
            acc2a[2 * c]     = __builtin_elementwise_fma(pv0, vl, acc2a[2 * c]);
            acc2a[2 * c + 1] = __builtin_elementwise_fma(pv0, vh, acc2a[2 * c + 1]);
            acc2b[2 * c]     = __builtin_elementwise_fma(pv1, vl, acc2b[2 * c]);
            acc2b[2 * c + 1] = __builtin_elementwise_fma(pv1, vh, acc2b[2 * c + 1]);
        }
        aa0 = fmaf(p0, xj.x, aa0); aa1 = fmaf(p0, xj.y, aa1); aa2 = fmaf(p0, xj.z, aa2);
        ab0 = fmaf(p1, xj.x, ab0); ab1 = fmaf(p1, xj.y, ab1); ab2 = fmaf(p1, xj.z, ab2);
    }

    // ---- write partials: stats [r][32], acc [c][r][36] contiguous per row
    pm[((size_t)r0 << 5) + cid] = m0;
    ps[((size_t)r0 << 5) + cid] = sum0;
    pm[((size_t)r1 << 5) + cid] = m1;
    ps[((size_t)r1 << 5) + cid] = sum1;
    {
        float* pb = pacc + ((size_t)cid * NRTOT + r0) * 36;
#pragma unroll
        for (int d4 = 0; d4 < 8; ++d4) {
            float4 st; st.x = acc2a[2*d4].x; st.y = acc2a[2*d4].y;
            st.z = acc2a[2*d4+1].x; st.w = acc2a[2*d4+1].y;
            *(float4*)(pb + (d4 << 2)) = st;
        }
        float4 st; st.x = aa0; st.y = aa1; st.z = aa2; st.w = 0.f;
        *(float4*)(pb + 32) = st;
    }
    {
        float* pb = pacc + ((size_t)cid * NRTOT + r1) * 36;
#pragma unroll
        for (int d4 = 0; d4 < 8; ++d4) {
            float4 st; st.x = acc2b[2*d4].x; st.y = acc2b[2*d4].y;
            st.z = acc2b[2*d4+1].x; st.w = acc2b[2*d4+1].y;
            *(float4*)(pb + (d4 << 2)) = st;
        }
        float4 st; st.x = ab0; st.y = ab1; st.z = ab2; st.w = 0.f;
        *(float4*)(pb + 32) = st;
    }
}

// ---------------------------------------------------------------- merge + epilogue + next-layer qkv
// 4 rows/block (wave-per-row). If Wqn != null, also computes next layer's
// q,k,v from the freshly updated h (weights LDS-broadcast; intra-wave
// LDS produce->consume pattern, proven in r9/r10).
__global__ __launch_bounds__(256) void k_mergefin(const float* __restrict__ pm,
                                                  const float* __restrict__ ps,
                                                  const float* __restrict__ pacc,
                                                  float* __restrict__ hg,
                                                  const float* __restrict__ xin,
                                                  float* __restrict__ xout,
                                                  const float* __restrict__ Wo,
                                                  const float* __restrict__ W1,
                                                  const float* __restrict__ W2,
                                                  const float* __restrict__ csp,
                                                  const float* __restrict__ Wqn,
                                                  const float* __restrict__ Wkn,
                                                  const float* __restrict__ Wvn,
                                                  float* __restrict__ qout,
                                                  float* __restrict__ kout,
                                                  float* __restrict__ vout) {
    __shared__ float wo_s[1024];
    __shared__ float w1_s[2048];
    __shared__ float w2_s[2048];
    __shared__ float wq_s[1024];
    __shared__ float wk_s[1024];
    __shared__ float wv_s[1024];
    __shared__ float ad_s[4][40];
    __shared__ float h1_s[4][36];
    __shared__ float h2_s[4][36];
    __shared__ float f_s[4][64];

    const int t = threadIdx.x, w = t >> 6, lane = t & 63;
    for (int i = t; i < 1024; i += 256) wo_s[i] = Wo[i];
    for (int i = t; i < 2048; i += 256) { w1_s[i] = W1[i]; w2_s[i] = W2[i]; }
    if (Wqn) {
        for (int i = t; i < 1024; i += 256) {
            wq_s[i] = Wqn[i]; wk_s[i] = Wkn[i]; wv_s[i] = Wvn[i];
        }
    }
    __syncthreads();

    const int r = (blockIdx.x << 2) + w;

    // merge stats across 32 chunks ([r][32] layout -> coalesced per wave)
    float pmv = NEGF, psv = 0.f;
    if (lane < NCHUNK) { pmv = pm[((size_t)r << 5) + lane]; psv = ps[((size_t)r << 5) + lane]; }
    float m_g = pmv;
#pragma unroll
    for (int off = 1; off < 64; off <<= 1) m_g = fmaxf(m_g, __shfl_xor(m_g, off));
    float scv = (lane < NCHUNK) ? exp2_fast(pmv - m_g) : 0.f;
    float sg = scv * psv;
#pragma unroll
    for (int off = 1; off < 64; off <<= 1) sg += __shfl_xor(sg, off);
    const float rinv = 1.0f / sg;

    // merged accumulator, lane = d (pacc [c][r][36], lane-contiguous reads)
    const int dl = (lane < 36) ? lane : 0;
    float ad = 0.f;
#pragma unroll
    for (int c = 0; c < NCHUNK; ++c) {
        float scc = __shfl(scv, c);
        float pv = pacc[((size_t)c * NRTOT + r) * 36 + dl];
        ad = fmaf(scc, pv, ad);
    }
    if (lane < 35) ad_s[w][lane] = ad;

    // Wo matmul: lane&31 = col (both halves compute redundantly)
    const int col = lane & 31;
    float hv = 0.f;
#pragma unroll
    for (int d = 0; d < 32; ++d) hv = fmaf(ad_s[w][d], wo_s[(d << 5) + col], hv);
    float h1 = 0.f;
    if (lane < 32) { h1 = hg[(((size_t)r) << 5) + lane] + hv * rinv; h1_s[w][lane] = h1; }

    // FF up: lane = u (64)
    float f = 0.f;
#pragma unroll
    for (int d = 0; d < 32; ++d) f = fmaf(h1_s[w][d], w1_s[(d << 6) + lane], f);
    f = fmaxf(f, 0.f);
    f_s[w][lane] = f;

    // FF down + residual: lane<32 = col
    float hnew = 0.f;
    if (lane < 32) {
        float v2a = 0.f;
#pragma unroll
        for (int u = 0; u < 64; ++u) v2a = fmaf(f_s[w][u], w2_s[(u << 5) + lane], v2a);
        hnew = h1 + v2a;
        hg[(((size_t)r) << 5) + lane] = hnew;
        h2_s[w][lane] = hnew;
    }

    // equivariant x update
    if (lane < 3) {
        float o  = ad_s[w][32 + lane] * rinv;
        float xi = xin[r * 3 + lane];
        xout[r * 3 + lane] = xi + csp[0] * (xi - o);
    }

    // fused next-layer qkv (lane<32 = output column)
    if (Wqn && lane < 32) {
        float aq = 0.f, ak = 0.f, av = 0.f;
#pragma unroll
        for (int d = 0; d < 32; ++d) {
            float hd = h2_s[w][d];
            aq = fmaf(hd, wq_s[(d << 5) + lane], aq);
            ak = fmaf(hd, wk_s[(d << 5) + lane], ak);
            av = fmaf(hd, wv_s[(d << 5) + lane], av);
        }
        qout[(((size_t)r) << 5) + lane] = aq;
        kout[(((size_t)r) << 5) + lane] = ak;
        vout[(((size_t)r) << 5) + lane] = av;
    }
}

// ---------------------------------------------------------------- pooling stage 1 (parallel)
__global__ __launch_bounds__(256) void k_pool(const float* __restrict__ h,
                                              float* __restrict__ pool_ws) {
    const int b = blockIdx.x >> 5, sub = blockIdx.x & 31;
    const int t = threadIdx.x, c = t & 31, g = t >> 5;
    float s = 0.f;
#pragma unroll
    for (int i = 0; i < 8; ++i) {
        int row = (sub << 6) + (g << 3) + i;
        s += h[(((size_t)((b << 11) + row)) << 5) + c];
    }
    __shared__ float pool[8][32];
    pool[g][c] = s;
    __syncthreads();
    if (t < 32) {
        float ss = 0.f;
#pragma unroll
        for (int gg = 0; gg < 8; ++gg) ss += pool[gg][t];
        pool_ws[((b << 5) + sub) * 32 + t] = ss;
    }
}

// ---------------------------------------------------------------- head (tiny)
__global__ __launch_bounds__(256) void k_head(const float* __restrict__ pool_ws,
                                              const float* __restrict__ Wf1,
                                              const float* __restrict__ bf1,
                                              const float* __restrict__ Wf2,
                                              const float* __restrict__ bf2,
                                              float* __restrict__ out) {
    __shared__ float pooled[4][32];
    __shared__ float a1[4][16];
    const int t = threadIdx.x;
    if (t < 128) {
        int b = t >> 5, c = t & 31;
        float ss = 0.f;
#pragma unroll
        for (int sub = 0; sub < 32; ++sub) ss += pool_ws[((b << 5) + sub) * 32 + c];
        pooled[b][c] = ss * (1.0f / N_);
    }
    __syncthreads();
    if (t < 64) {
        int b = t >> 4, u = t & 15;
        float a = bf1[u];
#pragma unroll
        for (int d = 0; d < 32; ++d) a += pooled[b][d] * Wf1[(d << 4) + u];
        a1[b][u] = fmaxf(a, 0.f);
    }
    __syncthreads();
    if (t < 12) {
        int b = t / 3, o = t - b * 3;
        float v = bf2[o];
#pragma unroll
        for (int e = 0; e < 16; ++e) v += a1[b][e] * Wf2[e * 3 + o];
        out[b * 3 + o] = v;
    }
}

// ---------------------------------------------------------------- launch
extern "C" void kernel_launch(void* const* d_in, const int* in_sizes, int n_in,
                              void* d_out, int out_size, void* d_ws, size_t ws_size,
                              hipStream_t stream) {
    const float* feats = (const float*)d_in[0];
    const float* coors = (const float*)d_in[1];
    const int*   adj   = (const int*)d_in[2];
    const float* W_in  = (const float*)d_in[3];
    const float* Wq    = (const float*)d_in[4];
    const float* Wk    = (const float*)d_in[5];
    const float* Wv    = (const float*)d_in[6];
    const float* Wo    = (const float*)d_in[7];
    const float* W1    = (const float*)d_in[8];
    const float* W2    = (const float*)d_in[9];
    const float* csc   = (const float*)d_in[10];
    const float* Wf1   = (const float*)d_in[11];
    const float* bf1   = (const float*)d_in[12];
    const float* Wf2   = (const float*)d_in[13];
    const float* bf2   = (const float*)d_in[14];

    const size_t BNH = (size_t)4 * N_ * H_;   // 262144
    float* ws = (float*)d_ws;
    float* h  = ws;
    float* q  = ws + BNH;
    float* k  = ws + 2 * BNH;
    float* v  = ws + 3 * BNH;
    float* x0 = ws + 4 * BNH;                          // 24576 floats
    float* x1 = x0 + (size_t)4 * N_ * 3;
    unsigned long long* mask = (unsigned long long*)(x1 + (size_t)4 * N_ * 3);  // 262144 u64
    float* pm   = (float*)(mask + 262144);             // 262144
    float* ps   = pm + (size_t)NCHUNK * NRTOT;         // 262144
    float* pacc = ps + (size_t)NCHUNK * NRTOT;         // 32*8192*36 floats (37.7MB)
    float* pool_ws = pacc + (size_t)NCHUNK * NRTOT * 36;  // 4096 floats

    k_adjmask<<<65536, 256, 0, stream>>>(adj, mask);
    k_init_qkv<<<1024, 256, 0, stream>>>(feats, W_in, Wq, Wk, Wv, h, q, k, v);

    const float* xin[3]  = {coors, x0, x1};
    float*       xout[3] = {x0, x1, x0};
    for (int l = 0; l < 3; ++l) {
        k_attn<<<512, 256, 0, stream>>>(q, k, v, xin[l], mask, pm, ps, pacc);
        const bool last = (l == 2);
        k_mergefin<<<2048, 256, 0, stream>>>(pm, ps, pacc, h, xin[l], xout[l],
                                             Wo + l * 1024, W1 + l * 2048, W2 + l * 2048,
                                             csc + l,
                                             last ? nullptr : Wq + (l + 1) * 1024,
                                             last ? nullptr : Wk + (l + 1) * 1024,
                                             last ? nullptr : Wv + (l + 1) * 1024,
                                             q, k, v);
    }
    k_pool<<<128, 256, 0, stream>>>(h, pool_ws);
    k_head<<<1, 256, 0, stream>>>(pool_ws, Wf1, bf1, Wf2, bf2, (float*)d_out);
}